// Round 1
// baseline (1581.915 us; speedup 1.0000x reference)
//
#include <hip/hip_runtime.h>
#include <stdint.h>

typedef unsigned short u16;
typedef __attribute__((ext_vector_type(8))) short bfrag;   // 8 x bf16 (4 VGPR)
typedef __attribute__((ext_vector_type(4))) float f32x4;   // MFMA accumulator

#define MFMA16(a,b,c) __builtin_amdgcn_mfma_f32_16x16x32_bf16(a,b,c,0,0,0)

__device__ __forceinline__ u16 f2b(float f){
  union { float f; uint32_t u; } v; v.f = f;
  uint32_t r = v.u + 0x7FFFu + ((v.u >> 16) & 1u);   // RNE, finite-only
  return (u16)(r >> 16);
}

typedef const __attribute__((address_space(1))) unsigned int* gas_t;
typedef __attribute__((address_space(3))) unsigned int* las_t;
__device__ __forceinline__ void async16(const u16* g, u16* l){
  // direct global->LDS, 16B per lane; LDS dest must be wave-uniform base (+lane*16 by HW)
  __builtin_amdgcn_global_load_lds((gas_t)g, (las_t)l, 16, 0, 0);
}

// ---------------- weight / input conversion ----------------
__global__ __launch_bounds__(256) void cvt_x_k(const float* __restrict__ x, u16* __restrict__ o, int n){
  int i = blockIdx.x*256 + threadIdx.x;
  if (i < n) o[i] = f2b(x[i]);
}
__global__ __launch_bounds__(256) void cvt_winit_k(const float* __restrict__ w, u16* __restrict__ o){
  int i = blockIdx.x*256 + threadIdx.x;          // out [512 n][256 k]
  int n = i >> 8, k = i & 255;
  o[i] = f2b(w[k*512 + n]);
}
__global__ __launch_bounds__(256) void cvt_qkv_k(const float* __restrict__ Wq, const float* __restrict__ Wk,
                                                 const float* __restrict__ Wv, u16* __restrict__ o){
  int i = blockIdx.x*256 + threadIdx.x;          // out [3][1536 j][512 d]
  int d = i & 511;
  int j = (i >> 9) % 1536;
  int l = i / (1536*512);
  int which = j >> 9, hk = j & 511, h = hk >> 6, k = hk & 63;
  const float* W = which==0 ? Wq : (which==1 ? Wk : Wv);
  o[i] = f2b(W[(((size_t)l*8 + h)*512 + d)*64 + k]);
}
__global__ __launch_bounds__(256) void cvt_wo_k(const float* __restrict__ W, u16* __restrict__ o){
  int i = blockIdx.x*256 + threadIdx.x;          // out [3][512 dout][512 hk]
  int hk = i & 511;
  int dout = (i >> 9) & 511;
  int l = i >> 18;
  int h = hk >> 6, k = hk & 63;
  o[i] = f2b(W[(((size_t)l*8 + h)*64 + k)*512 + dout]);
}
__global__ __launch_bounds__(256) void cvt_w1_k(const float* __restrict__ W, u16* __restrict__ o){
  int i = blockIdx.x*256 + threadIdx.x;          // out [3][2048 f][512 d]
  int d = i & 511;
  int f = (i >> 9) & 2047;
  int l = i >> 20;
  o[i] = f2b(W[((size_t)l*512 + d)*2048 + f]);
}
__global__ __launch_bounds__(256) void cvt_w2_k(const float* __restrict__ W, u16* __restrict__ o){
  int i = blockIdx.x*256 + threadIdx.x;          // out [3][512 d][2048 f]
  int f = i & 2047;
  int d = (i >> 11) & 511;
  int l = i >> 20;
  o[i] = f2b(W[((size_t)l*2048 + f)*512 + d]);
}
__global__ __launch_bounds__(256) void eot_k(const float* __restrict__ eot, float* __restrict__ hF, u16* __restrict__ hbf){
  int i = blockIdx.x*256 + threadIdx.x;          // [32 b][512 d]
  int b = i >> 9, d = i & 511;
  float v = eot[d];
  size_t idx = ((size_t)b*513 + 512)*512 + d;
  hF[idx] = v; hbf[idx] = f2b(v);
}

// ---------------- GEMM: C[M,N] = A[M,K](bf16) * BT[N,K](bf16)^T ----------------
// swizzle: chunk position c in a 4-chunk (64B) row holds source chunk c^(r&3)^((r>>2)&1)
template<bool BIAS,bool RELU,bool SKIP,bool OUTF,bool OUTB,bool REMAP>
__global__ __launch_bounds__(256,2) void gemm_k(
    const u16* __restrict__ A, const u16* __restrict__ BT,
    const float* __restrict__ bias, const float* __restrict__ skip,
    float* __restrict__ outF, u16* __restrict__ outB,
    int M, int N, int K)
{
  __shared__ u16 Ash[128*32];
  __shared__ u16 Bsh[128*32];
  const int tid = threadIdx.x;
  const int lane = tid & 63, wv = tid >> 6;
  const int mt = blockIdx.x, nt = blockIdx.y;
  const int wrow = (wv >> 1) << 6, wcol = (wv & 1) << 6;
  const int g = lane >> 4, ci = lane & 15;

  f32x4 acc[4][4];
  #pragma unroll
  for (int i=0;i<4;i++)
    #pragma unroll
    for (int j=0;j<4;j++) acc[i][j] = (f32x4){0.f,0.f,0.f,0.f};

  int aoff[4], boff[4];
  #pragma unroll
  for (int mi=0;mi<4;mi++){
    int rr = wrow + mi*16 + ci;
    aoff[mi] = (rr*4 + (g ^ (rr&3) ^ ((rr>>2)&1)))*8;
    int cc = wcol + mi*16 + ci;
    boff[mi] = (cc*4 + (g ^ (cc&3) ^ ((cc>>2)&1)))*8;
  }
  const int o0 = tid, o1 = 256 + tid;
  const int ra0 = o0>>2, ca0 = o0&3, ra1 = o1>>2, ca1 = o1&3;
  const int sa0 = ca0 ^ (ra0&3) ^ ((ra0>>2)&1);
  const int sa1 = ca1 ^ (ra1&3) ^ ((ra1>>2)&1);
  int arow0 = mt*128 + ra0; if (arow0 >= M) arow0 = M-1;
  int arow1 = mt*128 + ra1; if (arow1 >= M) arow1 = M-1;
  const int brow0 = nt*128 + ra0, brow1 = nt*128 + ra1;
  const u16* ga0 = A + (size_t)arow0*K + sa0*8;
  const u16* ga1 = A + (size_t)arow1*K + sa1*8;
  const u16* gb0 = BT + (size_t)brow0*K + sa0*8;
  const u16* gb1 = BT + (size_t)brow1*K + sa1*8;
  u16* la0 = &Ash[(      wv*64)*8];
  u16* la1 = &Ash[(256 + wv*64)*8];
  u16* lb0 = &Bsh[(      wv*64)*8];
  u16* lb1 = &Bsh[(256 + wv*64)*8];

  for (int kt = 0; kt < K; kt += 32){
    async16(ga0 + kt, la0);
    async16(ga1 + kt, la1);
    async16(gb0 + kt, lb0);
    async16(gb1 + kt, lb1);
    __syncthreads();
    bfrag a[4], b[4];
    #pragma unroll
    for (int mi=0;mi<4;mi++) a[mi] = *(const bfrag*)&Ash[aoff[mi]];
    #pragma unroll
    for (int ni=0;ni<4;ni++) b[ni] = *(const bfrag*)&Bsh[boff[ni]];
    #pragma unroll
    for (int mi=0;mi<4;mi++)
      #pragma unroll
      for (int ni=0;ni<4;ni++)
        acc[mi][ni] = MFMA16(a[mi], b[ni], acc[mi][ni]);
    __syncthreads();
  }

  #pragma unroll
  for (int mi=0;mi<4;mi++){
    #pragma unroll
    for (int r=0;r<4;r++){
      int gm = mt*128 + wrow + mi*16 + g*4 + r;
      if (gm >= M) continue;
      size_t orow = REMAP ? (size_t)(gm + (gm >> 9)) : (size_t)gm;
      #pragma unroll
      for (int ni=0;ni<4;ni++){
        int gn = nt*128 + wcol + ni*16 + ci;
        float v = acc[mi][ni][r];
        if (BIAS) v += bias[gn];
        if (SKIP) v += skip[(size_t)gm*N + gn];
        if (RELU) v = fmaxf(v, 0.f);
        if (OUTF) outF[orow*N + gn] = v;
        if (OUTB) outB[orow*N + gn] = f2b(v);
      }
    }
  }
}

// ---------------- attention: per (qtile16, batch, head), 1 wave ----------------
__global__ __launch_bounds__(64) void attn_k(const u16* __restrict__ qkv, u16* __restrict__ heads)
{
  const int qt = blockIdx.x, b = blockIdx.y, hh = blockIdx.z;
  const int lane = threadIdx.x;
  const int g = lane >> 4, ci = lane & 15;
  __shared__ u16 P_lds[16*40];     // padded stride 40 (80B) -> 2-way max on b128 reads
  __shared__ u16 V_lds[32*64];

  const size_t rowb = (size_t)b * 513;
  int q = qt*16 + ci; int qr = q < 513 ? q : 512;
  const u16* qp = qkv + (rowb + qr)*1536 + hh*64 + g*8;
  bfrag aq0 = *(const bfrag*)qp;
  bfrag aq1 = *(const bfrag*)(qp + 32);

  f32x4 hacc[4];
  #pragma unroll
  for (int dt=0;dt<4;dt++) hacc[dt] = (f32x4){0.f,0.f,0.f,0.f};
  float mrun[4] = {-1e30f,-1e30f,-1e30f,-1e30f};
  float srun[4] = {0.f,0.f,0.f,0.f};

  for (int np = 0; np < 17; ++np){
    int n0 = np*32;
    // stage V[n0..n0+32)[64] ; row = 128B = 8 chunks of 16B
    #pragma unroll
    for (int i=0;i<4;i++){
      int o = i*64 + lane;
      int r = o >> 3, c = o & 7;
      int n = n0 + r; int nr = n < 513 ? n : 512;
      async16(qkv + (rowb + nr)*1536 + 1024 + hh*64 + c*8, &V_lds[i*64*8]);
    }
    // S = Q K^T (two 16-col tiles)
    int n_a = n0 + ci, n_b = n0 + 16 + ci;
    int nra = n_a < 513 ? n_a : 512, nrb = n_b < 513 ? n_b : 512;
    const u16* kpa = qkv + (rowb + nra)*1536 + 512 + hh*64 + g*8;
    const u16* kpb = qkv + (rowb + nrb)*1536 + 512 + hh*64 + g*8;
    bfrag k0a = *(const bfrag*)kpa, k1a = *(const bfrag*)(kpa+32);
    bfrag k0b = *(const bfrag*)kpb, k1b = *(const bfrag*)(kpb+32);
    f32x4 s0 = (f32x4){0.f,0.f,0.f,0.f}, s1 = (f32x4){0.f,0.f,0.f,0.f};
    s0 = MFMA16(aq0, k0a, s0); s0 = MFMA16(aq1, k1a, s0);
    s1 = MFMA16(aq0, k0b, s1); s1 = MFMA16(aq1, k1b, s1);
    const bool va = n_a < 513, vb = n_b < 513;
    float pm[4];
    #pragma unroll
    for (int r=0;r<4;r++){
      s0[r] = va ? s0[r]*0.125f : -1e30f;
      s1[r] = vb ? s1[r]*0.125f : -1e30f;
      pm[r] = fmaxf(s0[r], s1[r]);
    }
    #pragma unroll
    for (int m=1;m<16;m<<=1){
      #pragma unroll
      for (int r=0;r<4;r++) pm[r] = fmaxf(pm[r], __shfl_xor(pm[r], m));
    }
    float f[4], psum[4];
    f32x4 p0, p1;
    #pragma unroll
    for (int r=0;r<4;r++){
      float mn = fmaxf(mrun[r], pm[r]);
      f[r] = __expf(mrun[r] - mn);
      mrun[r] = mn;
      p0[r] = __expf(s0[r] - mn);
      p1[r] = __expf(s1[r] - mn);
      psum[r] = p0[r] + p1[r];
    }
    #pragma unroll
    for (int m=1;m<16;m<<=1){
      #pragma unroll
      for (int r=0;r<4;r++) psum[r] += __shfl_xor(psum[r], m);
    }
    #pragma unroll
    for (int r=0;r<4;r++){
      srun[r] = srun[r]*f[r] + psum[r];
      P_lds[(g*4+r)*40 + ci]      = f2b(p0[r]);
      P_lds[(g*4+r)*40 + 16 + ci] = f2b(p1[r]);
    }
    #pragma unroll
    for (int dt=0;dt<4;dt++){
      hacc[dt][0]*=f[0]; hacc[dt][1]*=f[1]; hacc[dt][2]*=f[2]; hacc[dt][3]*=f[3];
    }
    __syncthreads();   // P writes visible + V staging landed (vmcnt/lgkmcnt drain)
    bfrag pa = *(const bfrag*)&P_lds[ci*40 + g*8];
    #pragma unroll
    for (int dt=0;dt<4;dt++){
      bfrag bv;
      #pragma unroll
      for (int j=0;j<8;j++) bv[j] = (short)V_lds[(g*8+j)*64 + dt*16 + ci];
      hacc[dt] = MFMA16(pa, bv, hacc[dt]);
    }
    __syncthreads();   // all reads done before next V stage overwrites
  }
  #pragma unroll
  for (int dt=0;dt<4;dt++){
    #pragma unroll
    for (int r=0;r<4;r++){
      int qg = qt*16 + g*4 + r;
      if (qg < 513)
        heads[(rowb + qg)*512 + hh*64 + dt*16 + ci] = f2b(hacc[dt][r] / srun[r]);
    }
  }
}

// ---------------- BatchNorm (train-mode, biased var) ----------------
#define NBSTAT 258
__global__ __launch_bounds__(256) void bn_stats_k(const float* __restrict__ in, float* __restrict__ p1, float* __restrict__ p2){
  int blk = blockIdx.x, t = threadIdx.x;
  int r0 = blk*64, r1 = r0+64 < 16416 ? r0+64 : 16416;
  float s0=0.f,q0=0.f,s1=0.f,q1=0.f;
  for (int r=r0;r<r1;r++){
    float a = in[(size_t)r*512 + t];       s0+=a; q0+=a*a;
    float b = in[(size_t)r*512 + 256 + t]; s1+=b; q1+=b*b;
  }
  p1[(size_t)t*NBSTAT + blk] = s0; p1[(size_t)(t+256)*NBSTAT + blk] = s1;
  p2[(size_t)t*NBSTAT + blk] = q0; p2[(size_t)(t+256)*NBSTAT + blk] = q1;
}
__global__ __launch_bounds__(256) void bn_fin_k(const float* __restrict__ p1, const float* __restrict__ p2,
                                               const float* __restrict__ gamma, const float* __restrict__ beta,
                                               float2* __restrict__ sc){
  int c = blockIdx.x*256 + threadIdx.x;   // grid = 2 blocks -> 512 channels
  float S=0.f,Q=0.f;
  for (int i=0;i<NBSTAT;i++){ S += p1[(size_t)c*NBSTAT+i]; Q += p2[(size_t)c*NBSTAT+i]; }
  const float invM = 1.0f/16416.0f;
  float mean = S*invM;
  float var  = Q*invM - mean*mean;
  float scl  = gamma[c] * rsqrtf(var + 1e-5f);
  sc[c] = make_float2(scl, beta[c] - mean*scl);
}
__global__ __launch_bounds__(256) void bn_apply_k(const float* __restrict__ in, const float2* __restrict__ sc,
                                                  float* __restrict__ outF, u16* __restrict__ outB){
  const int n4 = 16416*512/4;
  for (int i = blockIdx.x*256 + threadIdx.x; i < n4; i += gridDim.x*256){
    float4 v = ((const float4*)in)[i];
    int c0 = (i << 2) & 511;
    float2 a = sc[c0], b = sc[c0+1], c = sc[c0+2], d = sc[c0+3];
    v.x = v.x*a.x + a.y; v.y = v.y*b.x + b.y; v.z = v.z*c.x + c.y; v.w = v.w*d.x + d.y;
    ((float4*)outF)[i] = v;
    ushort4 u; u.x=f2b(v.x); u.y=f2b(v.y); u.z=f2b(v.z); u.w=f2b(v.w);
    ((ushort4*)outB)[i] = u;
  }
}

// ---------------- host launcher ----------------
static inline size_t alignup(size_t x){ return (x + 255) & ~(size_t)255; }

extern "C" void kernel_launch(void* const* d_in, const int* in_sizes, int n_in,
                              void* d_out, int out_size, void* d_ws, size_t ws_size,
                              hipStream_t stream)
{
  (void)in_sizes; (void)n_in; (void)out_size; (void)ws_size;
  const float* x      = (const float*)d_in[0];
  const float* W_init = (const float*)d_in[1];
  const float* b_init = (const float*)d_in[2];
  const float* eot    = (const float*)d_in[3];
  const float* Wq     = (const float*)d_in[4];
  const float* Wk     = (const float*)d_in[5];
  const float* Wv     = (const float*)d_in[6];
  const float* Wo     = (const float*)d_in[7];
  const float* bn1g   = (const float*)d_in[8];
  const float* bn1b   = (const float*)d_in[9];
  const float* W1     = (const float*)d_in[10];
  const float* b1     = (const float*)d_in[11];
  const float* W2     = (const float*)d_in[12];
  const float* b2     = (const float*)d_in[13];
  const float* bn2g   = (const float*)d_in[14];
  const float* bn2b   = (const float*)d_in[15];

  char* ws = (char*)d_ws;
  size_t o = 0;
  u16*    hbf    = (u16*)  (ws + o); o += alignup(16416ull*512*2);
  float*  hF     = (float*)(ws + o); o += alignup(16416ull*512*4);
  float*  bufB   = (float*)(ws + o); o += alignup(16416ull*512*4);
  u16*    heads  = (u16*)  (ws + o); o += alignup(16416ull*512*2);
  u16*    big    = (u16*)  (ws + o); o += alignup(16416ull*2048*2);   // union: xbf | qkv | ff
  u16*    winitT = (u16*)  (ws + o); o += alignup(512ull*256*2);
  u16*    wqkvT  = (u16*)  (ws + o); o += alignup(3ull*1536*512*2);
  u16*    woT    = (u16*)  (ws + o); o += alignup(3ull*512*512*2);
  u16*    w1T    = (u16*)  (ws + o); o += alignup(3ull*2048*512*2);
  u16*    w2T    = (u16*)  (ws + o); o += alignup(3ull*512*2048*2);
  float*  p1     = (float*)(ws + o); o += alignup(512ull*NBSTAT*4);
  float*  p2     = (float*)(ws + o); o += alignup(512ull*NBSTAT*4);
  float2* scv    = (float2*)(ws + o); o += alignup(512*8);
  u16* xbf = big; u16* qkv = big; u16* ffb = big;

  // conversions (inputs restored before every call -> redo every call)
  cvt_x_k    <<<16384,256,0,stream>>>(x, xbf, 16384*256);
  cvt_winit_k<<<  512,256,0,stream>>>(W_init, winitT);
  cvt_qkv_k  <<< 9216,256,0,stream>>>(Wq, Wk, Wv, wqkvT);
  cvt_wo_k   <<< 3072,256,0,stream>>>(Wo, woT);
  cvt_w1_k   <<<12288,256,0,stream>>>(W1, w1T);
  cvt_w2_k   <<<12288,256,0,stream>>>(W2, w2T);

  // h = x@W_init + b_init  (rows remapped b*513+n), eot row appended
  gemm_k<true,false,false,true,true,true><<<dim3(128,4),256,0,stream>>>(
      xbf, winitT, b_init, nullptr, hF, hbf, 16384, 512, 256);
  eot_k<<<64,256,0,stream>>>(eot, hF, hbf);

  for (int l = 0; l < 3; ++l){
    // QKV projection -> [16416][1536] (Q|K|V, head-major 64)
    gemm_k<false,false,false,false,true,false><<<dim3(129,12),256,0,stream>>>(
        hbf, wqkvT + (size_t)l*1536*512, nullptr, nullptr, nullptr, qkv, 16416, 1536, 512);
    // attention -> heads [16416][512]
    attn_k<<<dim3(33,32,8),64,0,stream>>>(qkv, heads);
    // out-proj + skip -> bufB (f32)
    gemm_k<false,false,true,true,false,false><<<dim3(129,4),256,0,stream>>>(
        heads, woT + (size_t)l*512*512, nullptr, hF, bufB, nullptr, 16416, 512, 512);
    // BN1
    bn_stats_k<<<NBSTAT,256,0,stream>>>(bufB, p1, p2);
    bn_fin_k  <<<2,256,0,stream>>>(p1, p2, bn1g + l*512, bn1b + l*512, scv);
    bn_apply_k<<<2048,256,0,stream>>>(bufB, scv, hF, hbf);
    // FFN
    gemm_k<true,true,false,false,true,false><<<dim3(129,16),256,0,stream>>>(
        hbf, w1T + (size_t)l*2048*512, b1 + l*2048, nullptr, nullptr, ffb, 16416, 2048, 512);
    gemm_k<true,false,true,true,false,false><<<dim3(129,4),256,0,stream>>>(
        ffb, w2T + (size_t)l*512*2048, b2 + l*512, hF, bufB, nullptr, 16416, 512, 2048);
    // BN2 (last layer writes final output)
    bn_stats_k<<<NBSTAT,256,0,stream>>>(bufB, p1, p2);
    bn_fin_k  <<<2,256,0,stream>>>(p1, p2, bn2g + l*512, bn2b + l*512, scv);
    bn_apply_k<<<2048,256,0,stream>>>(bufB, scv, (l==2) ? (float*)d_out : hF, hbf);
  }
}